// Round 1
// baseline (809.601 us; speedup 1.0000x reference)
//
#include <hip/hip_runtime.h>
#include <float.h>
#include <math.h>

#define N_NODES 50000
#define CIN 256
#define COUT 128
#define NCLS 7

static __device__ __forceinline__ float wave_sum(float v) {
#pragma unroll
  for (int off = 32; off > 0; off >>= 1) v += __shfl_xor(v, off, 64);
  return v;
}

// ---------------- CSR build ----------------

__global__ void hist_kernel(const int* __restrict__ rows, int* __restrict__ counts, int e) {
  int i = blockIdx.x * blockDim.x + threadIdx.x;
  if (i < e) atomicAdd(&counts[rows[i]], 1);
}

// single-block scan over counts[n] -> rowptr (exclusive), cursor (copy of rowptr)
// counts may alias cursor (read-before-write per index).
__global__ __launch_bounds__(1024) void scan_kernel(const int* __restrict__ counts,
                                                    int* __restrict__ rowptr,
                                                    int* __restrict__ cursor,
                                                    int n, int total) {
  __shared__ int sh[1024];
  __shared__ int carry_sh;
  int tid = threadIdx.x;
  if (tid == 0) carry_sh = 0;
  __syncthreads();
  for (int base = 0; base < n; base += 1024) {
    int i = base + tid;
    int v = (i < n) ? counts[i] : 0;
    sh[tid] = v;
    __syncthreads();
    for (int off = 1; off < 1024; off <<= 1) {
      int add = (tid >= off) ? sh[tid - off] : 0;
      __syncthreads();
      sh[tid] += add;
      __syncthreads();
    }
    int carry = carry_sh;
    int excl = sh[tid] - v;
    if (i < n) {
      rowptr[i] = carry + excl;
      cursor[i] = carry + excl;
    }
    __syncthreads();
    if (tid == 1023) carry_sh = carry + sh[1023];
    __syncthreads();
  }
  if (tid == 0) rowptr[n] = total;
}

__global__ void scatter_kernel(const int* __restrict__ rows, const int* __restrict__ cols,
                               const float* __restrict__ vals, int* __restrict__ cursor,
                               int* __restrict__ colv, float* __restrict__ valv, int e) {
  int i = blockIdx.x * blockDim.x + threadIdx.x;
  if (i < e) {
    int r = rows[i];
    int idx = atomicAdd(&cursor[r], 1);
    colv[idx] = cols[i];
    valv[idx] = vals[i];
  }
}

// ---------------- h = tanh(x @ W_in + b_in) ----------------
// BM=32 rows, BN=128 (all), BK=16. 256 threads.
__global__ __launch_bounds__(256) void gemm_tanh_kernel(const float* __restrict__ x,
                                                        const float* __restrict__ W,
                                                        const float* __restrict__ b,
                                                        float* __restrict__ h, int n) {
  __shared__ float xs[16][36];   // [BK][BM+pad4] -> float4-aligned, conflict-light
  __shared__ float wsh[16][COUT];
  int t = threadIdx.x;
  int block_row = blockIdx.x * 32;
  int tc = t & 31, tr = t >> 5;
  int c0 = tc * 4, r0 = tr * 4;
  float acc[4][4] = {};
  // x load mapping: float2 per thread
  int lr = t >> 3;          // 0..31
  int lk = (t & 7) * 2;     // 0,2,..,14
  int grow = block_row + lr;
  bool rvalid = grow < n;
  const float* xrow = x + (size_t)(rvalid ? grow : 0) * CIN;
  // w load mapping: 8 floats per thread
  int wr = t >> 4;          // 0..15
  int wc = (t & 15) * 8;

  for (int k0 = 0; k0 < CIN; k0 += 16) {
    float2 xv = rvalid ? *(const float2*)(xrow + k0 + lk) : make_float2(0.f, 0.f);
    xs[lk][lr] = xv.x;
    xs[lk + 1][lr] = xv.y;
    const float* wp = W + (size_t)(k0 + wr) * COUT + wc;
    float4 w0 = *(const float4*)wp;
    float4 w1 = *(const float4*)(wp + 4);
    *(float4*)&wsh[wr][wc] = w0;
    *(float4*)&wsh[wr][wc + 4] = w1;
    __syncthreads();
#pragma unroll
    for (int kk = 0; kk < 16; ++kk) {
      float4 xa = *(const float4*)&xs[kk][r0];
      float4 wv = *(const float4*)&wsh[kk][c0];
      float xr[4] = {xa.x, xa.y, xa.z, xa.w};
      float wvv[4] = {wv.x, wv.y, wv.z, wv.w};
#pragma unroll
      for (int i = 0; i < 4; ++i)
#pragma unroll
        for (int j = 0; j < 4; ++j) acc[i][j] = fmaf(xr[i], wvv[j], acc[i][j]);
    }
    __syncthreads();
  }
  float4 bv = *(const float4*)(b + c0);
  float bb[4] = {bv.x, bv.y, bv.z, bv.w};
#pragma unroll
  for (int i = 0; i < 4; ++i) {
    int row = block_row + r0 + i;
    if (row < n) {
      float4 o;
      o.x = tanhf(acc[i][0] + bb[0]);
      o.y = tanhf(acc[i][1] + bb[1]);
      o.z = tanhf(acc[i][2] + bb[2]);
      o.w = tanhf(acc[i][3] + bb[3]);
      *(float4*)&h[(size_t)row * COUT + c0] = o;
    }
  }
}

// ---------------- SpMM: out[r,:] = sum_e val * in[col,:], 128 channels ----------------
__global__ __launch_bounds__(256) void spmm_dense_kernel(const int* __restrict__ rowptr,
                                                         const int* __restrict__ colv,
                                                         const float* __restrict__ valv,
                                                         const float* __restrict__ xin,
                                                         float* __restrict__ xout, int n) {
  int r = blockIdx.x * 2 + (threadIdx.x >> 7);
  int c = threadIdx.x & 127;
  if (r >= n) return;
  int s = rowptr[r], e = rowptr[r + 1];
  float acc = 0.f;
  for (int i = s; i < e; ++i) {
    acc = fmaf(valv[i], xin[(size_t)colv[i] * COUT + c], acc);
  }
  xout[(size_t)r * COUT + c] = acc;
}

// ---------------- dn[r] = || low(r,:) - h(r,:) ||_2 ----------------
__global__ __launch_bounds__(256) void dn_kernel(const float* __restrict__ h,
                                                 const float* __restrict__ t1,
                                                 const float* __restrict__ t2,
                                                 const float* __restrict__ t3,
                                                 const float* __restrict__ delta,
                                                 const float* __restrict__ a,
                                                 float* __restrict__ dn, int n) {
  __shared__ float sh[4];
  int w = threadIdx.x >> 6;
  int r = blockIdx.x * 2 + (threadIdx.x >> 7);
  int c = threadIdx.x & 127;
  float d = delta[0], av = a[0];
  float cl2 = -3.f * d - av;
  float cl1 = 3.f * d * d + 2.f * d * av;
  float cl0 = -(d * d * d + d * d * av);
  float val = 0.f;
  if (r < n) {
    size_t idx = (size_t)r * COUT + c;
    float hv = h[idx];
    float low = t3[idx] + cl2 * t2[idx] + cl1 * t1[idx] + cl0 * hv;
    float diff = low - hv;
    val = diff * diff;
  }
  float s = wave_sum(val);
  if ((threadIdx.x & 63) == 0) sh[w] = s;
  __syncthreads();
  if ((threadIdx.x & 127) == 0 && r < n) dn[r] = sqrtf(sh[w] + sh[w + 1]);
}

// ---------------- hd = spmm(dn), 1 channel ----------------
__global__ void spmm_vec_kernel(const int* __restrict__ rowptr, const int* __restrict__ colv,
                                const float* __restrict__ valv, const float* __restrict__ dn,
                                float* __restrict__ hd, int n) {
  int r = blockIdx.x * blockDim.x + threadIdx.x;
  if (r >= n) return;
  int s = rowptr[r], e = rowptr[r + 1];
  float acc = 0.f;
  for (int i = s; i < e; ++i) acc = fmaf(valv[i], dn[colv[i]], acc);
  hd[r] = acc;
}

// ---------------- min/max over hd ----------------
__global__ __launch_bounds__(256) void minmax_partial_kernel(const float* __restrict__ hd,
                                                             float* __restrict__ partial, int n) {
  float mn = FLT_MAX, mx = -FLT_MAX;
  for (int i = blockIdx.x * blockDim.x + threadIdx.x; i < n; i += gridDim.x * blockDim.x) {
    float v = hd[i];
    mn = fminf(mn, v);
    mx = fmaxf(mx, v);
  }
#pragma unroll
  for (int off = 32; off > 0; off >>= 1) {
    mn = fminf(mn, __shfl_xor(mn, off, 64));
    mx = fmaxf(mx, __shfl_xor(mx, off, 64));
  }
  __shared__ float smn[4], smx[4];
  int w = threadIdx.x >> 6;
  if ((threadIdx.x & 63) == 0) { smn[w] = mn; smx[w] = mx; }
  __syncthreads();
  if (threadIdx.x == 0) {
    mn = fminf(fminf(smn[0], smn[1]), fminf(smn[2], smn[3]));
    mx = fmaxf(fmaxf(smx[0], smx[1]), fmaxf(smx[2], smx[3]));
    partial[blockIdx.x] = mn;
    partial[gridDim.x + blockIdx.x] = mx;
  }
}

__global__ __launch_bounds__(256) void minmax_final_kernel(const float* __restrict__ partial,
                                                           float* __restrict__ mnmx, int nb) {
  float mn = partial[threadIdx.x];
  float mx = partial[nb + threadIdx.x];
#pragma unroll
  for (int off = 32; off > 0; off >>= 1) {
    mn = fminf(mn, __shfl_xor(mn, off, 64));
    mx = fmaxf(mx, __shfl_xor(mx, off, 64));
  }
  __shared__ float smn[4], smx[4];
  int w = threadIdx.x >> 6;
  if ((threadIdx.x & 63) == 0) { smn[w] = mn; smx[w] = mx; }
  __syncthreads();
  if (threadIdx.x == 0) {
    mnmx[0] = fminf(fminf(smn[0], smn[1]), fminf(smn[2], smn[3]));
    mnmx[1] = fmaxf(fmaxf(smx[0], smx[1]), fmaxf(smx[2], smx[3]));
  }
}

// ---------------- final: normalize, mix, relu, @W_out + b_out, log_softmax ----------------
__global__ __launch_bounds__(256) void final_kernel(const float* __restrict__ h,
                                                    const float* __restrict__ t1,
                                                    const float* __restrict__ t2,
                                                    const float* __restrict__ t3,
                                                    const float* __restrict__ hd,
                                                    const float* __restrict__ mnmx,
                                                    const float* __restrict__ delta,
                                                    const float* __restrict__ a,
                                                    const float* __restrict__ W_out,
                                                    const float* __restrict__ b_out,
                                                    float* __restrict__ out, int n) {
  __shared__ float wsh[COUT * NCLS];
  __shared__ float bsh[NCLS];
  for (int i = threadIdx.x; i < COUT * NCLS; i += 256) wsh[i] = W_out[i];
  if (threadIdx.x < NCLS) bsh[threadIdx.x] = b_out[threadIdx.x];
  __syncthreads();
  int w = threadIdx.x >> 6;
  int lane = threadIdx.x & 63;
  int r = blockIdx.x * 4 + w;
  if (r >= n) return;
  float d = delta[0], av = a[0];
  float cl2 = -3.f * d - av;
  float cl1 = 3.f * d * d + 2.f * d * av;
  float cl0 = -(d * d * d + d * d * av);
  float ch2 = -3.f * d + av;
  float ch1 = 3.f * d * d - 2.f * d * av;
  float ch0 = d * d * av - d * d * d;
  float mn = mnmx[0], mx = mnmx[1];
  float normal = (hd[r] - mn) / (mx - mn);
  float onemn = 1.f - normal;
  size_t base = (size_t)r * COUT;
  float f[2];
#pragma unroll
  for (int p = 0; p < 2; ++p) {
    int c = lane + p * 64;
    size_t idx = base + c;
    float hv = h[idx], v1 = t1[idx], v2 = t2[idx], v3 = t3[idx];
    float low = v3 + cl2 * v2 + cl1 * v1 + cl0 * hv;
    float high = v3 + ch2 * v2 + ch1 * v1 + ch0 * hv;
    float fin = onemn * low + normal * high;
    f[p] = fmaxf(fin, 0.f);
  }
  float y[NCLS];
#pragma unroll
  for (int j = 0; j < NCLS; ++j) {
    float pv = f[0] * wsh[lane * NCLS + j] + f[1] * wsh[(lane + 64) * NCLS + j];
    y[j] = wave_sum(pv) + bsh[j];
  }
  if (lane == 0) {
    float m = y[0];
#pragma unroll
    for (int j = 1; j < NCLS; ++j) m = fmaxf(m, y[j]);
    float s = 0.f;
#pragma unroll
    for (int j = 0; j < NCLS; ++j) s += expf(y[j] - m);
    float lse = m + logf(s);
#pragma unroll
    for (int j = 0; j < NCLS; ++j) out[(size_t)r * NCLS + j] = y[j] - lse;
  }
}

extern "C" void kernel_launch(void* const* d_in, const int* in_sizes, int n_in,
                              void* d_out, int out_size, void* d_ws, size_t ws_size,
                              hipStream_t stream) {
  (void)n_in; (void)out_size; (void)ws_size;
  const float* x     = (const float*)d_in[0];
  const float* vals  = (const float*)d_in[1];
  const float* W_in  = (const float*)d_in[2];
  const float* b_in  = (const float*)d_in[3];
  const float* delta = (const float*)d_in[4];
  const float* a_in  = (const float*)d_in[5];
  const float* W_out = (const float*)d_in[6];
  const float* b_out = (const float*)d_in[7];
  const int* rows    = (const int*)d_in[8];
  const int* cols    = (const int*)d_in[9];
  float* out = (float*)d_out;
  const int n = N_NODES;
  const int e = in_sizes[1];

  char* p = (char*)d_ws;
  auto alloc = [&](size_t bytes) {
    char* r = p;
    p += (bytes + 255) & ~(size_t)255;
    return r;
  };
  float* h  = (float*)alloc((size_t)n * COUT * 4);
  float* t1 = (float*)alloc((size_t)n * COUT * 4);
  float* t2 = (float*)alloc((size_t)n * COUT * 4);
  float* t3 = (float*)alloc((size_t)n * COUT * 4);
  float* dn = (float*)alloc((size_t)n * 4);
  float* hd = (float*)alloc((size_t)n * 4);
  int* rowptr = (int*)alloc((size_t)(n + 1) * 4);
  int* cursor = (int*)alloc((size_t)n * 4);
  int* colv   = (int*)alloc((size_t)e * 4);
  float* valv = (float*)alloc((size_t)e * 4);
  float* partial = (float*)alloc(512 * 4);
  float* mnmx = (float*)alloc(2 * 4);

  // CSR build (cursor doubles as counts)
  hipMemsetAsync(cursor, 0, (size_t)n * 4, stream);
  hist_kernel<<<(e + 255) / 256, 256, 0, stream>>>(rows, cursor, e);
  scan_kernel<<<1, 1024, 0, stream>>>(cursor, rowptr, cursor, n, e);
  scatter_kernel<<<(e + 255) / 256, 256, 0, stream>>>(rows, cols, vals, cursor, colv, valv, e);

  // h = tanh(x @ W_in + b_in)
  gemm_tanh_kernel<<<(n + 31) / 32, 256, 0, stream>>>(x, W_in, b_in, h, n);

  // Tx1, Tx2, Tx3
  spmm_dense_kernel<<<(n + 1) / 2, 256, 0, stream>>>(rowptr, colv, valv, h, t1, n);
  spmm_dense_kernel<<<(n + 1) / 2, 256, 0, stream>>>(rowptr, colv, valv, t1, t2, n);
  spmm_dense_kernel<<<(n + 1) / 2, 256, 0, stream>>>(rowptr, colv, valv, t2, t3, n);

  // dn = ||low - h||
  dn_kernel<<<(n + 1) / 2, 256, 0, stream>>>(h, t1, t2, t3, delta, a_in, dn, n);

  // hd = spmm(dn)
  spmm_vec_kernel<<<(n + 255) / 256, 256, 0, stream>>>(rowptr, colv, valv, dn, hd, n);

  // min/max of hd
  minmax_partial_kernel<<<256, 256, 0, stream>>>(hd, partial, n);
  minmax_final_kernel<<<1, 256, 0, stream>>>(partial, mnmx, 256);

  // final fused epilogue
  final_kernel<<<(n + 3) / 4, 256, 0, stream>>>(h, t1, t2, t3, hd, mnmx, delta, a_in,
                                                W_out, b_out, out, n);
}

// Round 3
// 467.511 us; speedup vs baseline: 1.7317x; 1.7317x over previous
//
#include <hip/hip_runtime.h>
#include <float.h>
#include <math.h>

#define N_NODES 50000
#define CIN 256
#define COUT 128
#define NCLS 7

static __device__ __forceinline__ float wave_sum(float v) {
#pragma unroll
  for (int off = 32; off > 0; off >>= 1) v += __shfl_xor(v, off, 64);
  return v;
}

// order-preserving float<->uint encode for atomic min/max on signed floats
static __device__ __forceinline__ unsigned enc_f(float f) {
  unsigned u = __float_as_uint(f);
  return (u & 0x80000000u) ? ~u : (u | 0x80000000u);
}
static __device__ __forceinline__ float dec_f(unsigned u) {
  return __uint_as_float((u & 0x80000000u) ? (u & 0x7FFFFFFFu) : ~u);
}

// ---------------- CSR build ----------------

__global__ void hist_kernel(const int* __restrict__ rows, int* __restrict__ counts, int e) {
  int i = blockIdx.x * blockDim.x + threadIdx.x;
  if (i < e) atomicAdd(&counts[rows[i]], 1);
}

// per-block scan: 256 threads x 4 items = 1024/block. writes per-item exclusive
// prefix (within block) into rowptr, block total into bsum.
__global__ __launch_bounds__(256) void scan1_kernel(const int* __restrict__ counts,
                                                    int* __restrict__ rowptr,
                                                    int* __restrict__ bsum, int n) {
  __shared__ int sh[256];
  int t = threadIdx.x;
  int base = blockIdx.x * 1024 + t * 4;
  int v0 = (base + 0 < n) ? counts[base + 0] : 0;
  int v1 = (base + 1 < n) ? counts[base + 1] : 0;
  int v2 = (base + 2 < n) ? counts[base + 2] : 0;
  int v3 = (base + 3 < n) ? counts[base + 3] : 0;
  int s = v0 + v1 + v2 + v3;
  sh[t] = s;
  __syncthreads();
  for (int off = 1; off < 256; off <<= 1) {
    int add = (t >= off) ? sh[t - off] : 0;
    __syncthreads();
    sh[t] += add;
    __syncthreads();
  }
  int ex = sh[t] - s;
  if (base + 0 < n) rowptr[base + 0] = ex;
  ex += v0;
  if (base + 1 < n) rowptr[base + 1] = ex;
  ex += v1;
  if (base + 2 < n) rowptr[base + 2] = ex;
  ex += v2;
  if (base + 3 < n) rowptr[base + 3] = ex;
  if (t == 255) bsum[blockIdx.x] = sh[255];
}

// single-wave exclusive scan of block sums (nb <= 64)
__global__ void scan2_kernel(int* __restrict__ bsum, int nb) {
  int t = threadIdx.x;
  int v = (t < nb) ? bsum[t] : 0;
  int orig = v;
#pragma unroll
  for (int off = 1; off < 64; off <<= 1) {
    int u = __shfl_up(v, off, 64);
    if (t >= off) v += u;
  }
  if (t < nb) bsum[t] = v - orig;
}

// add block offsets, mirror into cursor, init rowptr[n] and minmax atomics
__global__ void scan3_kernel(int* __restrict__ rowptr, int* __restrict__ cursor,
                             const int* __restrict__ bsum, unsigned* __restrict__ mnmx_u,
                             int n, int e) {
  int i = blockIdx.x * blockDim.x + threadIdx.x;
  if (i < n) {
    int v = rowptr[i] + bsum[i >> 10];
    rowptr[i] = v;
    cursor[i] = v;
  }
  if (i == 0) {
    rowptr[n] = e;
    mnmx_u[0] = 0xFFFFFFFFu;  // min accumulator (encoded)
    mnmx_u[1] = 0u;           // max accumulator (encoded)
  }
}

__global__ void scatter_kernel(const int* __restrict__ rows, const int* __restrict__ cols,
                               const float* __restrict__ vals, int* __restrict__ cursor,
                               int* __restrict__ colv, float* __restrict__ valv, int e) {
  int i = blockIdx.x * blockDim.x + threadIdx.x;
  if (i < e) {
    int r = rows[i];
    int idx = atomicAdd(&cursor[r], 1);
    colv[idx] = cols[i];
    valv[idx] = vals[i];
  }
}

// ---------------- h = tanh(x @ W_in + b_in) ----------------
__global__ __launch_bounds__(256) void gemm_tanh_kernel(const float* __restrict__ x,
                                                        const float* __restrict__ W,
                                                        const float* __restrict__ b,
                                                        float* __restrict__ h, int n) {
  __shared__ float xs[16][36];
  __shared__ float wsh[16][COUT];
  int t = threadIdx.x;
  int block_row = blockIdx.x * 32;
  int tc = t & 31, tr = t >> 5;
  int c0 = tc * 4, r0 = tr * 4;
  float acc[4][4] = {};
  int lr = t >> 3;
  int lk = (t & 7) * 2;
  int grow = block_row + lr;
  bool rvalid = grow < n;
  const float* xrow = x + (size_t)(rvalid ? grow : 0) * CIN;
  int wr = t >> 4;
  int wc = (t & 15) * 8;

  for (int k0 = 0; k0 < CIN; k0 += 16) {
    float2 xv = rvalid ? *(const float2*)(xrow + k0 + lk) : make_float2(0.f, 0.f);
    xs[lk][lr] = xv.x;
    xs[lk + 1][lr] = xv.y;
    const float* wp = W + (size_t)(k0 + wr) * COUT + wc;
    float4 w0 = *(const float4*)wp;
    float4 w1 = *(const float4*)(wp + 4);
    *(float4*)&wsh[wr][wc] = w0;
    *(float4*)&wsh[wr][wc + 4] = w1;
    __syncthreads();
#pragma unroll
    for (int kk = 0; kk < 16; ++kk) {
      float4 xa = *(const float4*)&xs[kk][r0];
      float4 wv = *(const float4*)&wsh[kk][c0];
      float xr[4] = {xa.x, xa.y, xa.z, xa.w};
      float wvv[4] = {wv.x, wv.y, wv.z, wv.w};
#pragma unroll
      for (int i = 0; i < 4; ++i)
#pragma unroll
        for (int j = 0; j < 4; ++j) acc[i][j] = fmaf(xr[i], wvv[j], acc[i][j]);
    }
    __syncthreads();
  }
  float4 bv = *(const float4*)(b + c0);
  float bb[4] = {bv.x, bv.y, bv.z, bv.w};
#pragma unroll
  for (int i = 0; i < 4; ++i) {
    int row = block_row + r0 + i;
    if (row < n) {
      float4 o;
      o.x = tanhf(acc[i][0] + bb[0]);
      o.y = tanhf(acc[i][1] + bb[1]);
      o.z = tanhf(acc[i][2] + bb[2]);
      o.w = tanhf(acc[i][3] + bb[3]);
      *(float4*)&h[(size_t)row * COUT + c0] = o;
    }
  }
}

// ---------------- SpMM core: 32 lanes per row, float4 channels, unroll-4 ----------------
static __device__ __forceinline__ float4 spmm_row(const int* __restrict__ rowptr,
                                                  const int* __restrict__ colv,
                                                  const float* __restrict__ valv,
                                                  const float* __restrict__ xin,
                                                  int r, int c) {
  int s = rowptr[r], e = rowptr[r + 1];
  float4 acc = make_float4(0.f, 0.f, 0.f, 0.f);
  int i = s;
  for (; i + 4 <= e; i += 4) {
    int k0 = colv[i], k1 = colv[i + 1], k2 = colv[i + 2], k3 = colv[i + 3];
    float v0 = valv[i], v1 = valv[i + 1], v2 = valv[i + 2], v3 = valv[i + 3];
    float4 x0 = *(const float4*)&xin[(size_t)k0 * COUT + c];
    float4 x1 = *(const float4*)&xin[(size_t)k1 * COUT + c];
    float4 x2 = *(const float4*)&xin[(size_t)k2 * COUT + c];
    float4 x3 = *(const float4*)&xin[(size_t)k3 * COUT + c];
    acc.x = fmaf(v0, x0.x, acc.x); acc.y = fmaf(v0, x0.y, acc.y);
    acc.z = fmaf(v0, x0.z, acc.z); acc.w = fmaf(v0, x0.w, acc.w);
    acc.x = fmaf(v1, x1.x, acc.x); acc.y = fmaf(v1, x1.y, acc.y);
    acc.z = fmaf(v1, x1.z, acc.z); acc.w = fmaf(v1, x1.w, acc.w);
    acc.x = fmaf(v2, x2.x, acc.x); acc.y = fmaf(v2, x2.y, acc.y);
    acc.z = fmaf(v2, x2.z, acc.z); acc.w = fmaf(v2, x2.w, acc.w);
    acc.x = fmaf(v3, x3.x, acc.x); acc.y = fmaf(v3, x3.y, acc.y);
    acc.z = fmaf(v3, x3.z, acc.z); acc.w = fmaf(v3, x3.w, acc.w);
  }
  for (; i < e; ++i) {
    int k = colv[i];
    float v = valv[i];
    float4 xv = *(const float4*)&xin[(size_t)k * COUT + c];
    acc.x = fmaf(v, xv.x, acc.x); acc.y = fmaf(v, xv.y, acc.y);
    acc.z = fmaf(v, xv.z, acc.z); acc.w = fmaf(v, xv.w, acc.w);
  }
  return acc;
}

__global__ __launch_bounds__(256) void spmm_dense_kernel(const int* __restrict__ rowptr,
                                                         const int* __restrict__ colv,
                                                         const float* __restrict__ valv,
                                                         const float* __restrict__ xin,
                                                         float* __restrict__ xout, int n) {
  int r = blockIdx.x * 8 + (threadIdx.x >> 5);
  if (r >= n) return;
  int c = (threadIdx.x & 31) * 4;
  float4 acc = spmm_row(rowptr, colv, valv, xin, r, c);
  *(float4*)&xout[(size_t)r * COUT + c] = acc;
}

// Tx3 SpMM fused with dn[r] = ||low(r,:) - h(r,:)||_2
__global__ __launch_bounds__(256) void spmm_dense_dn_kernel(const int* __restrict__ rowptr,
                                                            const int* __restrict__ colv,
                                                            const float* __restrict__ valv,
                                                            const float* __restrict__ t2in,
                                                            float* __restrict__ t3out,
                                                            const float* __restrict__ h,
                                                            const float* __restrict__ t1,
                                                            const float* __restrict__ delta,
                                                            const float* __restrict__ a_s,
                                                            float* __restrict__ dn, int n) {
  int r = blockIdx.x * 8 + (threadIdx.x >> 5);
  if (r >= n) return;
  int c = (threadIdx.x & 31) * 4;
  float4 acc = spmm_row(rowptr, colv, valv, t2in, r, c);  // = t3 row r, 4 chans
  size_t idx = (size_t)r * COUT + c;
  *(float4*)&t3out[idx] = acc;

  float d = delta[0], av = a_s[0];
  float cl2 = -3.f * d - av;
  float cl1 = 3.f * d * d + 2.f * d * av;
  float cl0 = -(d * d * d + d * d * av);
  float4 hv = *(const float4*)&h[idx];
  float4 v1 = *(const float4*)&t1[idx];
  float4 v2 = *(const float4*)&t2in[idx];
  float dx = acc.x + cl2 * v2.x + cl1 * v1.x + cl0 * hv.x - hv.x;
  float dy = acc.y + cl2 * v2.y + cl1 * v1.y + cl0 * hv.y - hv.y;
  float dz = acc.z + cl2 * v2.z + cl1 * v1.z + cl0 * hv.z - hv.z;
  float dw = acc.w + cl2 * v2.w + cl1 * v1.w + cl0 * hv.w - hv.w;
  float ss = dx * dx + dy * dy + dz * dz + dw * dw;
#pragma unroll
  for (int off = 16; off > 0; off >>= 1) ss += __shfl_xor(ss, off, 64);
  if ((threadIdx.x & 31) == 0) dn[r] = sqrtf(ss);
}

// ---------------- hd = spmm(dn) fused with global min/max ----------------
__global__ __launch_bounds__(256) void spmm_vec_kernel(const int* __restrict__ rowptr,
                                                       const int* __restrict__ colv,
                                                       const float* __restrict__ valv,
                                                       const float* __restrict__ dn,
                                                       float* __restrict__ hd,
                                                       unsigned* __restrict__ mnmx_u, int n) {
  int r = blockIdx.x * blockDim.x + threadIdx.x;
  float acc = 0.f;
  bool valid = r < n;
  if (valid) {
    int s = rowptr[r], e = rowptr[r + 1];
    int i = s;
    float a0 = 0.f, a1 = 0.f, a2 = 0.f, a3 = 0.f;
    for (; i + 4 <= e; i += 4) {
      int k0 = colv[i], k1 = colv[i + 1], k2 = colv[i + 2], k3 = colv[i + 3];
      float v0 = valv[i], v1 = valv[i + 1], v2 = valv[i + 2], v3 = valv[i + 3];
      a0 = fmaf(v0, dn[k0], a0);
      a1 = fmaf(v1, dn[k1], a1);
      a2 = fmaf(v2, dn[k2], a2);
      a3 = fmaf(v3, dn[k3], a3);
    }
    acc = (a0 + a1) + (a2 + a3);
    for (; i < e; ++i) acc = fmaf(valv[i], dn[colv[i]], acc);
    hd[r] = acc;
  }
  float mn = valid ? acc : FLT_MAX;
  float mx = valid ? acc : -FLT_MAX;
#pragma unroll
  for (int off = 32; off > 0; off >>= 1) {
    mn = fminf(mn, __shfl_xor(mn, off, 64));
    mx = fmaxf(mx, __shfl_xor(mx, off, 64));
  }
  __shared__ float smn[4], smx[4];
  int w = threadIdx.x >> 6;
  if ((threadIdx.x & 63) == 0) { smn[w] = mn; smx[w] = mx; }
  __syncthreads();
  if (threadIdx.x == 0) {
    mn = fminf(fminf(smn[0], smn[1]), fminf(smn[2], smn[3]));
    mx = fmaxf(fmaxf(smx[0], smx[1]), fmaxf(smx[2], smx[3]));
    atomicMin(&mnmx_u[0], enc_f(mn));
    atomicMax(&mnmx_u[1], enc_f(mx));
  }
}

// ---------------- final: normalize, mix, relu, @W_out + b_out, log_softmax ----------------
__global__ __launch_bounds__(256) void final_kernel(const float* __restrict__ h,
                                                    const float* __restrict__ t1,
                                                    const float* __restrict__ t2,
                                                    const float* __restrict__ t3,
                                                    const float* __restrict__ hd,
                                                    const unsigned* __restrict__ mnmx_u,
                                                    const float* __restrict__ delta,
                                                    const float* __restrict__ a_s,
                                                    const float* __restrict__ W_out,
                                                    const float* __restrict__ b_out,
                                                    float* __restrict__ out, int n) {
  __shared__ float wsh[COUT * NCLS];
  __shared__ float bsh[NCLS];
  for (int i = threadIdx.x; i < COUT * NCLS; i += 256) wsh[i] = W_out[i];
  if (threadIdx.x < NCLS) bsh[threadIdx.x] = b_out[threadIdx.x];
  __syncthreads();
  int w = threadIdx.x >> 6;
  int lane = threadIdx.x & 63;
  int r = blockIdx.x * 4 + w;
  if (r >= n) return;
  float d = delta[0], av = a_s[0];
  float cl2 = -3.f * d - av;
  float cl1 = 3.f * d * d + 2.f * d * av;
  float cl0 = -(d * d * d + d * d * av);
  float ch2 = -3.f * d + av;
  float ch1 = 3.f * d * d - 2.f * d * av;
  float ch0 = d * d * av - d * d * d;
  float mn = dec_f(mnmx_u[0]), mx = dec_f(mnmx_u[1]);
  float normal = (hd[r] - mn) / (mx - mn);
  float onemn = 1.f - normal;
  size_t base = (size_t)r * COUT;
  float f[2];
#pragma unroll
  for (int p = 0; p < 2; ++p) {
    int c = lane + p * 64;
    size_t idx = base + c;
    float hv = h[idx], v1 = t1[idx], v2 = t2[idx], v3 = t3[idx];
    float low = v3 + cl2 * v2 + cl1 * v1 + cl0 * hv;
    float high = v3 + ch2 * v2 + ch1 * v1 + ch0 * hv;
    float fin = onemn * low + normal * high;
    f[p] = fmaxf(fin, 0.f);
  }
  float y[NCLS];
#pragma unroll
  for (int j = 0; j < NCLS; ++j) {
    float pv = f[0] * wsh[lane * NCLS + j] + f[1] * wsh[(lane + 64) * NCLS + j];
    y[j] = wave_sum(pv) + bsh[j];
  }
  if (lane == 0) {
    float m = y[0];
#pragma unroll
    for (int j = 1; j < NCLS; ++j) m = fmaxf(m, y[j]);
    float s = 0.f;
#pragma unroll
    for (int j = 0; j < NCLS; ++j) s += expf(y[j] - m);
    float lse = m + logf(s);
#pragma unroll
    for (int j = 0; j < NCLS; ++j) out[(size_t)r * NCLS + j] = y[j] - lse;
  }
}

extern "C" void kernel_launch(void* const* d_in, const int* in_sizes, int n_in,
                              void* d_out, int out_size, void* d_ws, size_t ws_size,
                              hipStream_t stream) {
  (void)n_in; (void)out_size; (void)ws_size;
  const float* x     = (const float*)d_in[0];
  const float* vals  = (const float*)d_in[1];
  const float* W_in  = (const float*)d_in[2];
  const float* b_in  = (const float*)d_in[3];
  const float* delta = (const float*)d_in[4];
  const float* a_in  = (const float*)d_in[5];
  const float* W_out = (const float*)d_in[6];
  const float* b_out = (const float*)d_in[7];
  const int* rows    = (const int*)d_in[8];
  const int* cols    = (const int*)d_in[9];
  float* out = (float*)d_out;
  const int n = N_NODES;
  const int e = in_sizes[1];

  char* p = (char*)d_ws;
  auto alloc = [&](size_t bytes) {
    char* r = p;
    p += (bytes + 255) & ~(size_t)255;
    return r;
  };
  float* h  = (float*)alloc((size_t)n * COUT * 4);
  float* t1 = (float*)alloc((size_t)n * COUT * 4);
  float* t2 = (float*)alloc((size_t)n * COUT * 4);
  float* t3 = (float*)alloc((size_t)n * COUT * 4);
  float* dn = (float*)alloc((size_t)n * 4);
  float* hd = (float*)alloc((size_t)n * 4);
  int* rowptr = (int*)alloc((size_t)(n + 1) * 4);
  int* cursor = (int*)alloc((size_t)n * 4);
  int* colv   = (int*)alloc((size_t)e * 4);
  float* valv = (float*)alloc((size_t)e * 4);
  int* bsum   = (int*)alloc(64 * 4);
  unsigned* mnmx_u = (unsigned*)alloc(2 * 4);

  // CSR build (cursor doubles as counts)
  hipMemsetAsync(cursor, 0, (size_t)n * 4, stream);
  hist_kernel<<<(e + 255) / 256, 256, 0, stream>>>(rows, cursor, e);
  const int nb = (n + 1023) / 1024;  // 49
  scan1_kernel<<<nb, 256, 0, stream>>>(cursor, rowptr, bsum, n);
  scan2_kernel<<<1, 64, 0, stream>>>(bsum, nb);
  scan3_kernel<<<(n + 255) / 256, 256, 0, stream>>>(rowptr, cursor, bsum, mnmx_u, n, e);
  scatter_kernel<<<(e + 255) / 256, 256, 0, stream>>>(rows, cols, vals, cursor, colv, valv, e);

  // h = tanh(x @ W_in + b_in)
  gemm_tanh_kernel<<<(n + 31) / 32, 256, 0, stream>>>(x, W_in, b_in, h, n);

  // Tx1, Tx2; Tx3 fused with dn
  spmm_dense_kernel<<<(n + 7) / 8, 256, 0, stream>>>(rowptr, colv, valv, h, t1, n);
  spmm_dense_kernel<<<(n + 7) / 8, 256, 0, stream>>>(rowptr, colv, valv, t1, t2, n);
  spmm_dense_dn_kernel<<<(n + 7) / 8, 256, 0, stream>>>(rowptr, colv, valv, t2, t3,
                                                        h, t1, delta, a_in, dn, n);

  // hd = spmm(dn) fused with min/max atomics
  spmm_vec_kernel<<<(n + 255) / 256, 256, 0, stream>>>(rowptr, colv, valv, dn, hd, mnmx_u, n);

  // final fused epilogue
  final_kernel<<<(n + 3) / 4, 256, 0, stream>>>(h, t1, t2, t3, hd, mnmx_u, delta, a_in,
                                                W_out, b_out, out, n);
}

// Round 6
// 463.428 us; speedup vs baseline: 1.7470x; 1.0088x over previous
//
#include <hip/hip_runtime.h>
#include <float.h>
#include <math.h>

#define N_NODES 50000
#define CIN 256
#define COUT 128
#define NCLS 7

// column-chunked CSR: bins keyed by (row, col >> CHUNK_SHIFT).
// 4096 cols/chunk * 512 B/row = 2 MB operand per chunk -> fits per-XCD L2.
#define CHUNK_SHIFT 12
#define CHK 13                    // ceil(50000 / 4096)
#define NBINS (N_NODES * CHK)     // 650000

static __device__ __forceinline__ float wave_sum(float v) {
#pragma unroll
  for (int off = 32; off > 0; off >>= 1) v += __shfl_xor(v, off, 64);
  return v;
}

// order-preserving float<->uint encode for atomic min/max on signed floats
static __device__ __forceinline__ unsigned enc_f(float f) {
  unsigned u = __float_as_uint(f);
  return (u & 0x80000000u) ? ~u : (u | 0x80000000u);
}
static __device__ __forceinline__ float dec_f(unsigned u) {
  return __uint_as_float((u & 0x80000000u) ? (u & 0x7FFFFFFFu) : ~u);
}

// ---------------- chunked-CSR build ----------------

__global__ void hist_kernel(const int* __restrict__ rows, const int* __restrict__ cols,
                            int* __restrict__ counts, int e) {
  int i = blockIdx.x * blockDim.x + threadIdx.x;
  if (i < e) atomicAdd(&counts[rows[i] * CHK + (cols[i] >> CHUNK_SHIFT)], 1);
}

// per-block scan: 256 threads x 4 items = 1024/block. writes per-item exclusive
// prefix (within block) into binptr, block total into bsum.
__global__ __launch_bounds__(256) void scan1_kernel(const int* __restrict__ counts,
                                                    int* __restrict__ binptr,
                                                    int* __restrict__ bsum, int n) {
  __shared__ int sh[256];
  int t = threadIdx.x;
  int base = blockIdx.x * 1024 + t * 4;
  int v0 = (base + 0 < n) ? counts[base + 0] : 0;
  int v1 = (base + 1 < n) ? counts[base + 1] : 0;
  int v2 = (base + 2 < n) ? counts[base + 2] : 0;
  int v3 = (base + 3 < n) ? counts[base + 3] : 0;
  int s = v0 + v1 + v2 + v3;
  sh[t] = s;
  __syncthreads();
  for (int off = 1; off < 256; off <<= 1) {
    int add = (t >= off) ? sh[t - off] : 0;
    __syncthreads();
    sh[t] += add;
    __syncthreads();
  }
  int ex = sh[t] - s;
  if (base + 0 < n) binptr[base + 0] = ex;
  ex += v0;
  if (base + 1 < n) binptr[base + 1] = ex;
  ex += v1;
  if (base + 2 < n) binptr[base + 2] = ex;
  ex += v2;
  if (base + 3 < n) binptr[base + 3] = ex;
  if (t == 255) bsum[blockIdx.x] = sh[255];
}

// single-block exclusive scan of block sums (nb <= 1024)
__global__ __launch_bounds__(1024) void scan2_kernel(int* __restrict__ bsum, int nb) {
  __shared__ int sh[1024];
  int t = threadIdx.x;
  int v = (t < nb) ? bsum[t] : 0;
  sh[t] = v;
  __syncthreads();
  for (int off = 1; off < 1024; off <<= 1) {
    int add = (t >= off) ? sh[t - off] : 0;
    __syncthreads();
    sh[t] += add;
    __syncthreads();
  }
  if (t < nb) bsum[t] = sh[t] - v;
}

// add block offsets, mirror into cursor, init binptr[NBINS] and minmax atomics
__global__ void scan3_kernel(int* __restrict__ binptr, int* __restrict__ cursor,
                             const int* __restrict__ bsum, unsigned* __restrict__ mnmx_u,
                             int n, int e) {
  int i = blockIdx.x * blockDim.x + threadIdx.x;
  if (i < n) {
    int v = binptr[i] + bsum[i >> 10];
    binptr[i] = v;
    cursor[i] = v;
  }
  if (i == 0) {
    binptr[n] = e;
    mnmx_u[0] = 0xFFFFFFFFu;  // min accumulator (encoded)
    mnmx_u[1] = 0u;           // max accumulator (encoded)
  }
}

__global__ void scatter_kernel(const int* __restrict__ rows, const int* __restrict__ cols,
                               const float* __restrict__ vals, int* __restrict__ cursor,
                               int* __restrict__ colv, float* __restrict__ valv, int e) {
  int i = blockIdx.x * blockDim.x + threadIdx.x;
  if (i < e) {
    int c = cols[i];
    int idx = atomicAdd(&cursor[rows[i] * CHK + (c >> CHUNK_SHIFT)], 1);
    colv[idx] = c;
    valv[idx] = vals[i];
  }
}

// ---------------- h = tanh(x @ W_in + b_in) ----------------
__global__ __launch_bounds__(256) void gemm_tanh_kernel(const float* __restrict__ x,
                                                        const float* __restrict__ W,
                                                        const float* __restrict__ b,
                                                        float* __restrict__ h, int n) {
  __shared__ float xs[16][36];
  __shared__ float wsh[16][COUT];
  int t = threadIdx.x;
  int block_row = blockIdx.x * 32;
  int tc = t & 31, tr = t >> 5;
  int c0 = tc * 4, r0 = tr * 4;
  float acc[4][4] = {};
  int lr = t >> 3;
  int lk = (t & 7) * 2;
  int grow = block_row + lr;
  bool rvalid = grow < n;
  const float* xrow = x + (size_t)(rvalid ? grow : 0) * CIN;
  int wr = t >> 4;
  int wc = (t & 15) * 8;

  for (int k0 = 0; k0 < CIN; k0 += 16) {
    float2 xv = rvalid ? *(const float2*)(xrow + k0 + lk) : make_float2(0.f, 0.f);
    xs[lk][lr] = xv.x;
    xs[lk + 1][lr] = xv.y;
    const float* wp = W + (size_t)(k0 + wr) * COUT + wc;
    float4 w0 = *(const float4*)wp;
    float4 w1 = *(const float4*)(wp + 4);
    *(float4*)&wsh[wr][wc] = w0;
    *(float4*)&wsh[wr][wc + 4] = w1;
    __syncthreads();
#pragma unroll
    for (int kk = 0; kk < 16; ++kk) {
      float4 xa = *(const float4*)&xs[kk][r0];
      float4 wv = *(const float4*)&wsh[kk][c0];
      float xr[4] = {xa.x, xa.y, xa.z, xa.w};
      float wvv[4] = {wv.x, wv.y, wv.z, wv.w};
#pragma unroll
      for (int i = 0; i < 4; ++i)
#pragma unroll
        for (int j = 0; j < 4; ++j) acc[i][j] = fmaf(xr[i], wvv[j], acc[i][j]);
    }
    __syncthreads();
  }
  float4 bv = *(const float4*)(b + c0);
  float bb[4] = {bv.x, bv.y, bv.z, bv.w};
#pragma unroll
  for (int i = 0; i < 4; ++i) {
    int row = block_row + r0 + i;
    if (row < n) {
      float4 o;
      o.x = tanhf(acc[i][0] + bb[0]);
      o.y = tanhf(acc[i][1] + bb[1]);
      o.z = tanhf(acc[i][2] + bb[2]);
      o.w = tanhf(acc[i][3] + bb[3]);
      *(float4*)&h[(size_t)row * COUT + c0] = o;
    }
  }
}

// ---------------- SpMM core: 32 lanes per row, float4 channels, unroll-4 ----------------
// edges arrive chunk-ordered (ascending col>>CHUNK_SHIFT) -> L2-friendly gather window
static __device__ __forceinline__ float4 spmm_row(const int* __restrict__ binptr,
                                                  const int* __restrict__ colv,
                                                  const float* __restrict__ valv,
                                                  const float* __restrict__ xin,
                                                  int r, int c) {
  int s = binptr[r * CHK];
  int e = binptr[r * CHK + CHK];
  float4 acc = make_float4(0.f, 0.f, 0.f, 0.f);
  int i = s;
  for (; i + 4 <= e; i += 4) {
    int k0 = colv[i], k1 = colv[i + 1], k2 = colv[i + 2], k3 = colv[i + 3];
    float v0 = valv[i], v1 = valv[i + 1], v2 = valv[i + 2], v3 = valv[i + 3];
    float4 x0 = *(const float4*)&xin[(size_t)k0 * COUT + c];
    float4 x1 = *(const float4*)&xin[(size_t)k1 * COUT + c];
    float4 x2 = *(const float4*)&xin[(size_t)k2 * COUT + c];
    float4 x3 = *(const float4*)&xin[(size_t)k3 * COUT + c];
    acc.x = fmaf(v0, x0.x, acc.x); acc.y = fmaf(v0, x0.y, acc.y);
    acc.z = fmaf(v0, x0.z, acc.z); acc.w = fmaf(v0, x0.w, acc.w);
    acc.x = fmaf(v1, x1.x, acc.x); acc.y = fmaf(v1, x1.y, acc.y);
    acc.z = fmaf(v1, x1.z, acc.z); acc.w = fmaf(v1, x1.w, acc.w);
    acc.x = fmaf(v2, x2.x, acc.x); acc.y = fmaf(v2, x2.y, acc.y);
    acc.z = fmaf(v2, x2.z, acc.z); acc.w = fmaf(v2, x2.w, acc.w);
    acc.x = fmaf(v3, x3.x, acc.x); acc.y = fmaf(v3, x3.y, acc.y);
    acc.z = fmaf(v3, x3.z, acc.z); acc.w = fmaf(v3, x3.w, acc.w);
  }
  for (; i < e; ++i) {
    int k = colv[i];
    float v = valv[i];
    float4 xv = *(const float4*)&xin[(size_t)k * COUT + c];
    acc.x = fmaf(v, xv.x, acc.x); acc.y = fmaf(v, xv.y, acc.y);
    acc.z = fmaf(v, xv.z, acc.z); acc.w = fmaf(v, xv.w, acc.w);
  }
  return acc;
}

__global__ __launch_bounds__(256) void spmm_dense_kernel(const int* __restrict__ binptr,
                                                         const int* __restrict__ colv,
                                                         const float* __restrict__ valv,
                                                         const float* __restrict__ xin,
                                                         float* __restrict__ xout, int n) {
  int r = blockIdx.x * 8 + (threadIdx.x >> 5);
  if (r >= n) return;
  int c = (threadIdx.x & 31) * 4;
  float4 acc = spmm_row(binptr, colv, valv, xin, r, c);
  *(float4*)&xout[(size_t)r * COUT + c] = acc;
}

// Tx3 SpMM fused with dn[r] = ||low(r,:) - h(r,:)||_2
__global__ __launch_bounds__(256) void spmm_dense_dn_kernel(const int* __restrict__ binptr,
                                                            const int* __restrict__ colv,
                                                            const float* __restrict__ valv,
                                                            const float* __restrict__ t2in,
                                                            float* __restrict__ t3out,
                                                            const float* __restrict__ h,
                                                            const float* __restrict__ t1,
                                                            const float* __restrict__ delta,
                                                            const float* __restrict__ a_s,
                                                            float* __restrict__ dn, int n) {
  int r = blockIdx.x * 8 + (threadIdx.x >> 5);
  if (r >= n) return;
  int c = (threadIdx.x & 31) * 4;
  float4 acc = spmm_row(binptr, colv, valv, t2in, r, c);  // = t3 row r, 4 chans
  size_t idx = (size_t)r * COUT + c;
  *(float4*)&t3out[idx] = acc;

  float d = delta[0], av = a_s[0];
  float cl2 = -3.f * d - av;
  float cl1 = 3.f * d * d + 2.f * d * av;
  float cl0 = -(d * d * d + d * d * av);
  float4 hv = *(const float4*)&h[idx];
  float4 v1 = *(const float4*)&t1[idx];
  float4 v2 = *(const float4*)&t2in[idx];
  float dx = acc.x + cl2 * v2.x + cl1 * v1.x + cl0 * hv.x - hv.x;
  float dy = acc.y + cl2 * v2.y + cl1 * v1.y + cl0 * hv.y - hv.y;
  float dz = acc.z + cl2 * v2.z + cl1 * v1.z + cl0 * hv.z - hv.z;
  float dw = acc.w + cl2 * v2.w + cl1 * v1.w + cl0 * hv.w - hv.w;
  float ss = dx * dx + dy * dy + dz * dz + dw * dw;
#pragma unroll
  for (int off = 16; off > 0; off >>= 1) ss += __shfl_xor(ss, off, 64);
  if ((threadIdx.x & 31) == 0) dn[r] = sqrtf(ss);
}

// ---------------- hd = spmm(dn) fused with global min/max ----------------
__global__ __launch_bounds__(256) void spmm_vec_kernel(const int* __restrict__ binptr,
                                                       const int* __restrict__ colv,
                                                       const float* __restrict__ valv,
                                                       const float* __restrict__ dn,
                                                       float* __restrict__ hd,
                                                       unsigned* __restrict__ mnmx_u, int n) {
  int r = blockIdx.x * blockDim.x + threadIdx.x;
  float acc = 0.f;
  bool valid = r < n;
  if (valid) {
    int s = binptr[r * CHK], e = binptr[r * CHK + CHK];
    int i = s;
    float a0 = 0.f, a1 = 0.f, a2 = 0.f, a3 = 0.f;
    for (; i + 4 <= e; i += 4) {
      int k0 = colv[i], k1 = colv[i + 1], k2 = colv[i + 2], k3 = colv[i + 3];
      float v0 = valv[i], v1 = valv[i + 1], v2 = valv[i + 2], v3 = valv[i + 3];
      a0 = fmaf(v0, dn[k0], a0);
      a1 = fmaf(v1, dn[k1], a1);
      a2 = fmaf(v2, dn[k2], a2);
      a3 = fmaf(v3, dn[k3], a3);
    }
    acc = (a0 + a1) + (a2 + a3);
    for (; i < e; ++i) acc = fmaf(valv[i], dn[colv[i]], acc);
    hd[r] = acc;
  }
  float mn = valid ? acc : FLT_MAX;
  float mx = valid ? acc : -FLT_MAX;
#pragma unroll
  for (int off = 32; off > 0; off >>= 1) {
    mn = fminf(mn, __shfl_xor(mn, off, 64));
    mx = fmaxf(mx, __shfl_xor(mx, off, 64));
  }
  __shared__ float smn[4], smx[4];
  int w = threadIdx.x >> 6;
  if ((threadIdx.x & 63) == 0) { smn[w] = mn; smx[w] = mx; }
  __syncthreads();
  if (threadIdx.x == 0) {
    mn = fminf(fminf(smn[0], smn[1]), fminf(smn[2], smn[3]));
    mx = fmaxf(fmaxf(smx[0], smx[1]), fmaxf(smx[2], smx[3]));
    atomicMin(&mnmx_u[0], enc_f(mn));
    atomicMax(&mnmx_u[1], enc_f(mx));
  }
}

// ---------------- final: normalize, mix, relu, @W_out + b_out, log_softmax ----------------
__global__ __launch_bounds__(256) void final_kernel(const float* __restrict__ h,
                                                    const float* __restrict__ t1,
                                                    const float* __restrict__ t2,
                                                    const float* __restrict__ t3,
                                                    const float* __restrict__ hd,
                                                    const unsigned* __restrict__ mnmx_u,
                                                    const float* __restrict__ delta,
                                                    const float* __restrict__ a_s,
                                                    const float* __restrict__ W_out,
                                                    const float* __restrict__ b_out,
                                                    float* __restrict__ out, int n) {
  __shared__ float wsh[COUT * NCLS];
  __shared__ float bsh[NCLS];
  for (int i = threadIdx.x; i < COUT * NCLS; i += 256) wsh[i] = W_out[i];
  if (threadIdx.x < NCLS) bsh[threadIdx.x] = b_out[threadIdx.x];
  __syncthreads();
  int w = threadIdx.x >> 6;
  int lane = threadIdx.x & 63;
  int r = blockIdx.x * 4 + w;
  if (r >= n) return;
  float d = delta[0], av = a_s[0];
  float cl2 = -3.f * d - av;
  float cl1 = 3.f * d * d + 2.f * d * av;
  float cl0 = -(d * d * d + d * d * av);
  float ch2 = -3.f * d + av;
  float ch1 = 3.f * d * d - 2.f * d * av;
  float ch0 = d * d * av - d * d * d;
  float mn = dec_f(mnmx_u[0]), mx = dec_f(mnmx_u[1]);
  float normal = (hd[r] - mn) / (mx - mn);
  float onemn = 1.f - normal;
  size_t base = (size_t)r * COUT;
  float f[2];
#pragma unroll
  for (int p = 0; p < 2; ++p) {
    int c = lane + p * 64;
    size_t idx = base + c;
    float hv = h[idx], v1 = t1[idx], v2 = t2[idx], v3 = t3[idx];
    float low = v3 + cl2 * v2 + cl1 * v1 + cl0 * hv;
    float high = v3 + ch2 * v2 + ch1 * v1 + ch0 * hv;
    float fin = onemn * low + normal * high;
    f[p] = fmaxf(fin, 0.f);
  }
  float y[NCLS];
#pragma unroll
  for (int j = 0; j < NCLS; ++j) {
    float pv = f[0] * wsh[lane * NCLS + j] + f[1] * wsh[(lane + 64) * NCLS + j];
    y[j] = wave_sum(pv) + bsh[j];
  }
  if (lane == 0) {
    float m = y[0];
#pragma unroll
    for (int j = 1; j < NCLS; ++j) m = fmaxf(m, y[j]);
    float s = 0.f;
#pragma unroll
    for (int j = 0; j < NCLS; ++j) s += expf(y[j] - m);
    float lse = m + logf(s);
#pragma unroll
    for (int j = 0; j < NCLS; ++j) out[(size_t)r * NCLS + j] = y[j] - lse;
  }
}

extern "C" void kernel_launch(void* const* d_in, const int* in_sizes, int n_in,
                              void* d_out, int out_size, void* d_ws, size_t ws_size,
                              hipStream_t stream) {
  (void)n_in; (void)out_size; (void)ws_size;
  const float* x     = (const float*)d_in[0];
  const float* vals  = (const float*)d_in[1];
  const float* W_in  = (const float*)d_in[2];
  const float* b_in  = (const float*)d_in[3];
  const float* delta = (const float*)d_in[4];
  const float* a_in  = (const float*)d_in[5];
  const float* W_out = (const float*)d_in[6];
  const float* b_out = (const float*)d_in[7];
  const int* rows    = (const int*)d_in[8];
  const int* cols    = (const int*)d_in[9];
  float* out = (float*)d_out;
  const int n = N_NODES;
  const int e = in_sizes[1];
  const int nbins = NBINS;

  char* p = (char*)d_ws;
  auto alloc = [&](size_t bytes) {
    char* r = p;
    p += (bytes + 255) & ~(size_t)255;
    return r;
  };
  float* h  = (float*)alloc((size_t)n * COUT * 4);
  float* t1 = (float*)alloc((size_t)n * COUT * 4);
  float* t2 = (float*)alloc((size_t)n * COUT * 4);
  float* t3 = (float*)alloc((size_t)n * COUT * 4);
  float* dn = (float*)alloc((size_t)n * 4);
  float* hd = (float*)alloc((size_t)n * 4);
  int* binptr = (int*)alloc((size_t)(nbins + 1) * 4);
  int* cursor = (int*)alloc((size_t)nbins * 4);
  int* colv   = (int*)alloc((size_t)e * 4);
  float* valv = (float*)alloc((size_t)e * 4);
  int* bsum   = (int*)alloc(1024 * 4);
  unsigned* mnmx_u = (unsigned*)alloc(2 * 4);

  // chunked-CSR build (cursor doubles as counts)
  hipMemsetAsync(cursor, 0, (size_t)nbins * 4, stream);
  hist_kernel<<<(e + 255) / 256, 256, 0, stream>>>(rows, cols, cursor, e);
  const int nb = (nbins + 1023) / 1024;  // 635 <= 1024
  scan1_kernel<<<nb, 256, 0, stream>>>(cursor, binptr, bsum, nbins);
  scan2_kernel<<<1, 1024, 0, stream>>>(bsum, nb);
  scan3_kernel<<<(nbins + 255) / 256, 256, 0, stream>>>(binptr, cursor, bsum, mnmx_u, nbins, e);
  scatter_kernel<<<(e + 255) / 256, 256, 0, stream>>>(rows, cols, vals, cursor, colv, valv, e);

  // h = tanh(x @ W_in + b_in)
  gemm_tanh_kernel<<<(n + 31) / 32, 256, 0, stream>>>(x, W_in, b_in, h, n);

  // Tx1, Tx2; Tx3 fused with dn
  spmm_dense_kernel<<<(n + 7) / 8, 256, 0, stream>>>(binptr, colv, valv, h, t1, n);
  spmm_dense_kernel<<<(n + 7) / 8, 256, 0, stream>>>(binptr, colv, valv, t1, t2, n);
  spmm_dense_dn_kernel<<<(n + 7) / 8, 256, 0, stream>>>(binptr, colv, valv, t2, t3,
                                                        h, t1, delta, a_in, dn, n);

  // hd = spmm(dn) fused with min/max atomics
  spmm_vec_kernel<<<(n + 255) / 256, 256, 0, stream>>>(binptr, colv, valv, dn, hd, mnmx_u, n);

  // final fused epilogue
  final_kernel<<<(n + 3) / 4, 256, 0, stream>>>(h, t1, t2, t3, hd, mnmx_u, delta, a_in,
                                                W_out, b_out, out, n);
}